// Round 10
// baseline (226.805 us; speedup 1.0000x reference)
//
#include <hip/hip_runtime.h>
#include <math.h>

// Problem constants (from reference): DM=512, DS=16, K=4, EXPAND=1
#define DMc   512
#define DIc   512
#define DSc   16
#define KCc   4
#define DTRc  32          // (512+15)//16
#define NXDc  64          // DTR + 2*DS
#define LLEN  2048
#define BBc   4
#define BLT   (BBc*LLEN)  // 8192

// chunked scan config
#define NCH   128         // chunks per sequence
#define CLEN  (LLEN/NCH)  // 16

typedef __attribute__((ext_vector_type(8))) short short8;
typedef __attribute__((ext_vector_type(8))) unsigned short ushort8;
typedef __attribute__((ext_vector_type(4))) unsigned short bf16x4_t;
typedef __attribute__((ext_vector_type(4))) float f32x4;

__device__ __forceinline__ float sigmoidf_(float x) { return 1.f / (1.f + __expf(-x)); }

// round-to-nearest-even f32 -> bf16 bits
__device__ __forceinline__ unsigned short f2bf(float x) {
    unsigned int u = __float_as_uint(x);
    u = (u + 0x7FFFu + ((u >> 16) & 1u)) >> 16;
    return (unsigned short)u;
}
__device__ __forceinline__ float bf2f(unsigned short u) {
    return __uint_as_float((unsigned int)u << 16);
}
__device__ __forceinline__ short8 pack8(float4 a, float4 b) {
    short8 r;
    r[0] = (short)f2bf(a.x); r[1] = (short)f2bf(a.y);
    r[2] = (short)f2bf(a.z); r[3] = (short)f2bf(a.w);
    r[4] = (short)f2bf(b.x); r[5] = (short)f2bf(b.y);
    r[6] = (short)f2bf(b.z); r[7] = (short)f2bf(b.w);
    return r;
}

// ---------------------------------------------------------------------------
// f32 -> bf16 conversion of W_in, W_out only (x is stage-converted in gemm1)
// ---------------------------------------------------------------------------
#define CW1 (1024 * DMc / 8)       // W_in
#define CW2 (DMc * DIc / 8)        // W_out
__global__ __launch_bounds__(256) void convert2_kernel(const float* __restrict__ Win,
                                                       const float* __restrict__ Wout,
                                                       unsigned short* __restrict__ Wb,
                                                       unsigned short* __restrict__ Wob)
{
    int i = blockIdx.x * 256 + threadIdx.x;
    const float* src; unsigned short* dst;
    if (i < CW1)             { src = Win;  dst = Wb;  }
    else if (i < CW1 + CW2)  { src = Wout; dst = Wob; i -= CW1; }
    else return;
    float4 a = ((const float4*)src)[2 * i];
    float4 b = ((const float4*)src)[2 * i + 1];
    ushort8 o;
    o[0] = f2bf(a.x); o[1] = f2bf(a.y); o[2] = f2bf(a.z); o[3] = f2bf(a.w);
    o[4] = f2bf(b.x); o[5] = f2bf(b.y); o[6] = f2bf(b.z); o[7] = f2bf(b.w);
    ((ushort8*)dst)[i] = o;
}

// ---------------------------------------------------------------------------
// bf16 MFMA GEMM: C[M,N] = A[M,K] * B[N,K]^T, f32 accumulate.
// 128x128 tile, BK=32, 4 waves. XCD-aware bijective block swizzle (nwg%8==0).
// AF32==1: A is f32, converted to bf16 during LDS staging (x input).
// OBF==1: bf16 output. EPI==1: clip to [-1000,1000], NaN->0 (f32 path).
// ---------------------------------------------------------------------------
template<int EPI, int OBF, int AF32>
__global__ __launch_bounds__(256) void gemm_mfma(const unsigned short* __restrict__ Ab16,
                                                 const float* __restrict__ Af32,
                                                 const unsigned short* __restrict__ Bw,
                                                 float* __restrict__ Cf,
                                                 unsigned short* __restrict__ Cb,
                                                 int N, int Kd)
{
    const int nwg  = gridDim.x * gridDim.y;
    const int orig = blockIdx.y * gridDim.x + blockIdx.x;
    const int lg   = (orig & 7) * (nwg >> 3) + (orig >> 3);
    const int bx   = lg % gridDim.x;
    const int by   = lg / gridDim.x;

    __shared__ short As[128][40];
    __shared__ short Bs[128][40];
    const int tid  = threadIdx.x;
    const int lane = tid & 63;
    const int wv   = tid >> 6;
    const int wr   = wv >> 1;
    const int wc   = wv & 1;
    const int fr   = lane & 15;
    const int fq   = lane >> 4;

    const int rowA0 = by * 128;
    const int rowB0 = bx * 128;

    const int r0 = tid >> 2,        s0 = (tid & 3) << 3;
    const int r1 = (tid + 256) >> 2, s1 = s0;

    f32x4 acc[4][4];
#pragma unroll
    for (int m = 0; m < 4; ++m)
#pragma unroll
        for (int n = 0; n < 4; ++n) acc[m][n] = (f32x4){0.f, 0.f, 0.f, 0.f};

    for (int k0 = 0; k0 < Kd; k0 += 32) {
        short8 a0, a1;
        if (AF32) {
            const float* p0 = Af32 + (size_t)(rowA0 + r0) * Kd + k0 + s0;
            const float* p1 = Af32 + (size_t)(rowA0 + r1) * Kd + k0 + s1;
            a0 = pack8(*(const float4*)p0, *(const float4*)(p0 + 4));
            a1 = pack8(*(const float4*)p1, *(const float4*)(p1 + 4));
        } else {
            a0 = *(const short8*)(Ab16 + (size_t)(rowA0 + r0) * Kd + k0 + s0);
            a1 = *(const short8*)(Ab16 + (size_t)(rowA0 + r1) * Kd + k0 + s1);
        }
        short8 b0 = *(const short8*)(Bw + (size_t)(rowB0 + r0) * Kd + k0 + s0);
        short8 b1 = *(const short8*)(Bw + (size_t)(rowB0 + r1) * Kd + k0 + s1);
        __syncthreads();
        *(short8*)&As[r0][s0] = a0;
        *(short8*)&As[r1][s1] = a1;
        *(short8*)&Bs[r0][s0] = b0;
        *(short8*)&Bs[r1][s1] = b1;
        __syncthreads();

        short8 af[4], bf[4];
#pragma unroll
        for (int m = 0; m < 4; ++m)
            af[m] = *(const short8*)&As[wr * 64 + m * 16 + fr][fq << 3];
#pragma unroll
        for (int n = 0; n < 4; ++n)
            bf[n] = *(const short8*)&Bs[wc * 64 + n * 16 + fr][fq << 3];
#pragma unroll
        for (int m = 0; m < 4; ++m)
#pragma unroll
            for (int n = 0; n < 4; ++n)
                acc[m][n] = __builtin_amdgcn_mfma_f32_16x16x32_bf16(af[m], bf[n], acc[m][n], 0, 0, 0);
    }

    const int crow0 = rowA0 + wr * 64 + (fq << 2);
    const int ccol0 = rowB0 + wc * 64 + fr;
#pragma unroll
    for (int m = 0; m < 4; ++m)
#pragma unroll
        for (int n = 0; n < 4; ++n)
#pragma unroll
            for (int j = 0; j < 4; ++j) {
                float v = acc[m][n][j];
                if (EPI) v = (v != v) ? 0.f : fminf(fmaxf(v, -1000.f), 1000.f);
                size_t off = (size_t)(crow0 + m * 16 + j) * N + ccol0 + n * 16;
                if (OBF) Cb[off] = f2bf(v);
                else     Cf[off] = v;
            }
}

// ---------------------------------------------------------------------------
// Depthwise causal conv (K=4) + bias + SiLU, bf16 in (x-half of xzb), bf16 out.
// ---------------------------------------------------------------------------
__global__ __launch_bounds__(256) void conv_silu_kernel(const unsigned short* __restrict__ xzb,
                                                        const float* __restrict__ cw,
                                                        const float* __restrict__ cb,
                                                        unsigned short* __restrict__ xcb)
{
    int gid = blockIdx.x * 256 + threadIdx.x;   // over BLT*DIc/8 = 2^19
    int d8 = gid & 63;
    int l  = (gid >> 6) & (LLEN - 1);
    int b  = gid >> 17;
    int d0 = d8 << 3;

    float s[8];
#pragma unroll
    for (int j = 0; j < 8; ++j) s[j] = cb[d0 + j];
#pragma unroll
    for (int k = 0; k < KCc; ++k) {
        int ls = l + k - (KCc - 1);
        if (ls >= 0) {
            ushort8 v = *(const ushort8*)(xzb + (((size_t)(b * LLEN + ls)) << 10) + d0);
#pragma unroll
            for (int j = 0; j < 8; ++j)
                s[j] += bf2f(v[j]) * cw[(d0 + j) * KCc + k];
        }
    }
    ushort8 o;
#pragma unroll
    for (int j = 0; j < 8; ++j) {
        float v = s[j] * sigmoidf_(s[j]);
        o[j] = f2bf(v);
    }
    *(ushort8*)(xcb + ((size_t)gid << 3)) = o;
}

// ---------------------------------------------------------------------------
// Fused x_dbl + dt kernel. Per 64-row block:
//   Phase A: xdbl[64x64] = xc[64x512](bf16) @ Wxp[64x512]^T, kept in LDS;
//            cols 32:64 (B,C) written packed to bcbuf[8192][32].
//   Phase B: dt[64x512] = softplus(xdbl[:,0:32] @ Wdt[512x32]^T + b_dt) -> dtz.
// xdbl never touches HBM.
// ---------------------------------------------------------------------------
__global__ __launch_bounds__(256) void xdbl_dt_kernel(const unsigned short* __restrict__ xcb,
                                                      const float* __restrict__ Wxp,
                                                      const float* __restrict__ Wdt,
                                                      const float* __restrict__ bdt,
                                                      float* __restrict__ bcbuf,
                                                      float* __restrict__ dtz)
{
    __shared__ float As[16][68];
    __shared__ float Bs[16][68];
    __shared__ float xd_s[64][68];    // pad 68: rows spread over 8 banks
    __shared__ float Wdt_s[64][33];   // pad 33: 2-way max on compute reads

    const int tid  = threadIdx.x;
    const int tx   = tid & 15;
    const int ty   = tid >> 4;
    const int arow = tid >> 2;
    const int akq  = (tid & 3) << 2;
    const int row0 = blockIdx.x * 64;

    const unsigned short* Ab = xcb + (size_t)(row0 + arow) * DIc + akq;
    const float*          Bb = Wxp + (size_t)arow * DIc + akq;

    float acc[4][4] = {};
    for (int k0 = 0; k0 < DIc; k0 += 16) {
        bf16x4_t av = *(const bf16x4_t*)(Ab + k0);
        float4   bv = *(const float4*)(Bb + k0);
        __syncthreads();
        As[akq + 0][arow] = bf2f(av[0]); As[akq + 1][arow] = bf2f(av[1]);
        As[akq + 2][arow] = bf2f(av[2]); As[akq + 3][arow] = bf2f(av[3]);
        Bs[akq + 0][arow] = bv.x; Bs[akq + 1][arow] = bv.y;
        Bs[akq + 2][arow] = bv.z; Bs[akq + 3][arow] = bv.w;
        __syncthreads();
#pragma unroll
        for (int k = 0; k < 16; ++k) {
            float4 a = *(const float4*)&As[k][ty << 2];
            float4 b = *(const float4*)&Bs[k][tx << 2];
            float ar[4] = {a.x, a.y, a.z, a.w};
            float br[4] = {b.x, b.y, b.z, b.w};
#pragma unroll
            for (int i = 0; i < 4; ++i)
#pragma unroll
                for (int j = 0; j < 4; ++j)
                    acc[i][j] += ar[i] * br[j];
        }
    }

    // write xdbl tile to LDS; B/C cols (32:64) packed to bcbuf
#pragma unroll
    for (int i = 0; i < 4; ++i) {
        int row = (ty << 2) + i;
        *(float4*)&xd_s[row][tx << 2] = make_float4(acc[i][0], acc[i][1], acc[i][2], acc[i][3]);
        if (tx >= 8)
            *(float4*)(bcbuf + (size_t)(row0 + row) * 32 + ((tx - 8) << 2))
                = make_float4(acc[i][0], acc[i][1], acc[i][2], acc[i][3]);
    }

    // Phase B: dt projection from LDS xdbl
    for (int c0 = 0; c0 < DIc; c0 += 64) {
        __syncthreads();
        {
            int wr_ = tid >> 2, wc_ = (tid & 3) << 3;
            const float* src = Wdt + (size_t)(c0 + wr_) * DTRc + wc_;
            float4 w0 = *(const float4*)src;
            float4 w1 = *(const float4*)(src + 4);
            Wdt_s[wr_][wc_ + 0] = w0.x; Wdt_s[wr_][wc_ + 1] = w0.y;
            Wdt_s[wr_][wc_ + 2] = w0.z; Wdt_s[wr_][wc_ + 3] = w0.w;
            Wdt_s[wr_][wc_ + 4] = w1.x; Wdt_s[wr_][wc_ + 5] = w1.y;
            Wdt_s[wr_][wc_ + 6] = w1.z; Wdt_s[wr_][wc_ + 7] = w1.w;
        }
        __syncthreads();
        float4 bd4 = *(const float4*)(bdt + c0 + (tx << 2));
        float bd[4] = {bd4.x, bd4.y, bd4.z, bd4.w};
#pragma unroll
        for (int i = 0; i < 4; ++i) {
            int row = (ty << 2) + i;
            float v[4];
#pragma unroll
            for (int j = 0; j < 4; ++j) {
                int c = (tx << 2) + j;
                float s = bd[j];
#pragma unroll
                for (int k = 0; k < DTRc; ++k)
                    s += xd_s[row][k] * Wdt_s[c][k];
                v[j] = fmaxf(s, 0.f) + log1pf(__expf(-fabsf(s)));
            }
            *(float4*)(dtz + (size_t)(row0 + row) * DIc + c0 + (tx << 2))
                = make_float4(v[0], v[1], v[2], v[3]);
        }
    }
}

// ---------------------------------------------------------------------------
// Chunked parallel scan. dt f32 in dtz; B/C f32 in bcbuf[8192][32];
// z bf16 in xzb cols 512+; xc bf16 in xcb. hstate bf16 (h_end / h_in).
// ---------------------------------------------------------------------------
__device__ __forceinline__ size_t hs_off(int b, int c, int s, int d) {
    return ((size_t)((b * NCH + c) * DSc + s) << 9) + d;
}

__global__ __launch_bounds__(256) void scan_phase1(const float* __restrict__ dtz,
                                                   const unsigned short* __restrict__ xcb,
                                                   const float* __restrict__ bcbuf,
                                                   const float* __restrict__ A_log,
                                                   unsigned short* __restrict__ hstate,
                                                   float* __restrict__ sdtbuf)
{
    int half = blockIdx.x & 1;
    int c    = (blockIdx.x >> 1) & (NCH - 1);
    int b    = blockIdx.x >> 8;
    int d    = (half << 8) + threadIdx.x;
    int row0 = b * LLEN + c * CLEN;

    __shared__ float bc[CLEN][32];   // [t][0:16]=B, [t][16:32]=C
    {
        int r = threadIdx.x >> 5, col = threadIdx.x & 31;
        const float* src = bcbuf + (size_t)row0 * 32;
        bc[r][col]     = src[r * 32 + col];
        bc[r + 8][col] = src[(r + 8) * 32 + col];
    }

    float A[DSc];
#pragma unroll
    for (int s = 0; s < DSc; ++s) A[s] = -__expf(A_log[d * DSc + s]);

    float dtv[CLEN], xcv[CLEN];
#pragma unroll
    for (int t = 0; t < CLEN; ++t) {
        dtv[t] = dtz[((size_t)(row0 + t) << 9) + d];
        xcv[t] = bf2f(xcb[((size_t)(row0 + t) << 9) + d]);
    }
    __syncthreads();

    float h[DSc] = {};
    float Sdt = 0.f;
#pragma unroll
    for (int t = 0; t < CLEN; ++t) {
        float dBx = dtv[t] * xcv[t];
        Sdt += dtv[t];
#pragma unroll
        for (int s = 0; s < DSc; ++s)
            h[s] = __expf(dtv[t] * A[s]) * h[s] + dBx * bc[t][s];
    }
#pragma unroll
    for (int s = 0; s < DSc; ++s) hstate[hs_off(b, c, s, d)] = f2bf(h[s]);
    sdtbuf[((size_t)(b * NCH + c) << 9) + d] = Sdt;
}

__global__ __launch_bounds__(64) void scan_phase2(unsigned short* __restrict__ hstate,
                                                  const float* __restrict__ sdtbuf,
                                                  const float* __restrict__ A_log)
{
    int gid = blockIdx.x * 64 + threadIdx.x;    // over B*DSc*DIc = 32768
    int d = gid & (DIc - 1);
    int s = (gid >> 9) & (DSc - 1);
    int b = gid >> 13;

    float A = -__expf(A_log[d * DSc + s]);
    float h = 0.f;
    for (int c = 0; c < NCH; ++c) {
        size_t o = hs_off(b, c, s, d);
        float he  = bf2f(hstate[o]);
        float Sdt = sdtbuf[((size_t)(b * NCH + c) << 9) + d];
        hstate[o] = f2bf(h);
        h = __expf(A * Sdt) * h + he;
    }
}

__global__ __launch_bounds__(256) void scan_phase3(const float* __restrict__ dtz,
                                                   const unsigned short* __restrict__ xcb,
                                                   const float* __restrict__ bcbuf,
                                                   const unsigned short* __restrict__ xzb,
                                                   const unsigned short* __restrict__ hstate,
                                                   const float* __restrict__ A_log,
                                                   const float* __restrict__ Dp,
                                                   unsigned short* __restrict__ yb)
{
    int half = blockIdx.x & 1;
    int c    = (blockIdx.x >> 1) & (NCH - 1);
    int b    = blockIdx.x >> 8;
    int d    = (half << 8) + threadIdx.x;
    int row0 = b * LLEN + c * CLEN;

    __shared__ float bc[CLEN][32];   // [t][0:16]=B, [t][16:32]=C
    {
        int r = threadIdx.x >> 5, col = threadIdx.x & 31;
        const float* src = bcbuf + (size_t)row0 * 32;
        bc[r][col]     = src[r * 32 + col];
        bc[r + 8][col] = src[(r + 8) * 32 + col];
    }

    float A[DSc];
#pragma unroll
    for (int s = 0; s < DSc; ++s) A[s] = -__expf(A_log[d * DSc + s]);
    float Dv = Dp[d];

    float dtv[CLEN], xcv[CLEN], zv[CLEN];
#pragma unroll
    for (int t = 0; t < CLEN; ++t) {
        dtv[t] = dtz[((size_t)(row0 + t) << 9) + d];
        xcv[t] = bf2f(xcb[((size_t)(row0 + t) << 9) + d]);
        zv[t]  = bf2f(xzb[((size_t)(row0 + t) << 10) + DIc + d]);
    }

    float h[DSc];
#pragma unroll
    for (int s = 0; s < DSc; ++s) h[s] = bf2f(hstate[hs_off(b, c, s, d)]);  // h_in
    __syncthreads();

#pragma unroll
    for (int t = 0; t < CLEN; ++t) {
        float dBx = dtv[t] * xcv[t];
        float acc = 0.f;
#pragma unroll
        for (int s = 0; s < DSc; ++s) {
            float dA = __expf(dtv[t] * A[s]);
            h[s] = dA * h[s] + dBx * bc[t][s];
            acc += h[s] * bc[t][DSc + s];
        }
        float yv = (acc + xcv[t] * Dv) * (zv[t] * sigmoidf_(zv[t]));
        yb[((size_t)(row0 + t) << 9) + d] = f2bf(yv);
    }
}

// ---------------------------------------------------------------------------
extern "C" void kernel_launch(void* const* d_in, const int* in_sizes, int n_in,
                              void* d_out, int out_size, void* d_ws, size_t ws_size,
                              hipStream_t stream)
{
    const float* x      = (const float*)d_in[0];
    const float* W_in   = (const float*)d_in[1];
    const float* conv_w = (const float*)d_in[2];
    const float* conv_b = (const float*)d_in[3];
    const float* W_xp   = (const float*)d_in[4];
    const float* W_dt   = (const float*)d_in[5];
    const float* b_dt   = (const float*)d_in[6];
    const float* A_log  = (const float*)d_in[7];
    const float* D_par  = (const float*)d_in[8];
    const float* W_out  = (const float*)d_in[9];
    float* out = (float*)d_out;

    // workspace layout (~62 MB)
    unsigned short* yb   = (unsigned short*)d_ws;            // [8192,512]  bf16: y
    unsigned short* xzb  = yb  + (size_t)BLT * DIc;          // [8192,1024] bf16: xz
    unsigned short* xcb  = xzb + (size_t)BLT * 1024;         // [8192,512]  bf16: xc
    unsigned short* Wb   = xcb + (size_t)BLT * DIc;          // [1024,512]  bf16
    unsigned short* Wob  = Wb  + (size_t)1024 * DMc;         // [512,512]   bf16
    float* bcbuf  = (float*)(Wob + (size_t)DMc * DIc);       // [8192,32]   f32: B,C
    float* dtz    = bcbuf + (size_t)BLT * 32;                // [8192,512]  f32: dt
    unsigned short* hstate = (unsigned short*)(dtz + (size_t)BLT * DIc); // [4,128,16,512] bf16
    float* sdtbuf = (float*)(hstate + (size_t)BBc * NCH * DSc * DIc);    // [4,128,512] f32

    // 0. f32 -> bf16 conversions (W_in, W_out)
    convert2_kernel<<<(CW1 + CW2 + 255) / 256, 256, 0, stream>>>(W_in, W_out, Wb, Wob);

    // 1. xz = x @ W_in^T (M=8192,N=1024,K=512), f32 A staged->bf16, bf16 out
    gemm_mfma<0, 1, 1><<<dim3(1024 / 128, BLT / 128), 256, 0, stream>>>(
        nullptr, x, Wb, nullptr, xzb, 1024, DMc);

    // 2. depthwise causal conv + SiLU -> xcb (bf16, 8-wide)
    conv_silu_kernel<<<(BLT * DIc / 8) / 256, 256, 0, stream>>>(xzb, conv_w, conv_b, xcb);

    // 3+4. fused x_dbl + dt: bcbuf (B,C) + dtz
    xdbl_dt_kernel<<<BLT / 64, 256, 0, stream>>>(xcb, W_xp, W_dt, b_dt, bcbuf, dtz);

    // 5. chunked parallel scan; y (bf16) into yb
    scan_phase1<<<BBc * NCH * 2, 256, 0, stream>>>(dtz, xcb, bcbuf, A_log, hstate, sdtbuf);
    scan_phase2<<<(BBc * DSc * DIc) / 64, 64, 0, stream>>>(hstate, sdtbuf, A_log);
    scan_phase3<<<BBc * NCH * 2, 256, 0, stream>>>(dtz, xcb, bcbuf, xzb, hstate,
                                                   A_log, D_par, yb);

    // 6. out = clip(y @ W_out^T) (M=8192,N=512,K=512), f32 out
    gemm_mfma<1, 0, 0><<<dim3(DMc / 128, BLT / 128), 256, 0, stream>>>(
        yb, nullptr, Wob, out, nullptr, DMc, DMc);
}

// Round 11
// 188.645 us; speedup vs baseline: 1.2023x; 1.2023x over previous
//
#include <hip/hip_runtime.h>
#include <math.h>

// Problem constants (from reference): DM=512, DS=16, K=4, EXPAND=1
#define DMc   512
#define DIc   512
#define DSc   16
#define KCc   4
#define DTRc  32          // (512+15)//16
#define NXDc  64          // DTR + 2*DS
#define LLEN  2048
#define BBc   4
#define BLT   (BBc*LLEN)  // 8192

// chunked scan config
#define NCH   128         // chunks per sequence
#define CLEN  (LLEN/NCH)  // 16

typedef __attribute__((ext_vector_type(8))) short short8;
typedef __attribute__((ext_vector_type(8))) unsigned short ushort8;
typedef __attribute__((ext_vector_type(4))) unsigned short bf16x4_t;
typedef __attribute__((ext_vector_type(4))) float f32x4;

__device__ __forceinline__ float sigmoidf_(float x) { return 1.f / (1.f + __expf(-x)); }

// round-to-nearest-even f32 -> bf16 bits
__device__ __forceinline__ unsigned short f2bf(float x) {
    unsigned int u = __float_as_uint(x);
    u = (u + 0x7FFFu + ((u >> 16) & 1u)) >> 16;
    return (unsigned short)u;
}
__device__ __forceinline__ float bf2f(unsigned short u) {
    return __uint_as_float((unsigned int)u << 16);
}
__device__ __forceinline__ short8 pack8(float4 a, float4 b) {
    short8 r;
    r[0] = (short)f2bf(a.x); r[1] = (short)f2bf(a.y);
    r[2] = (short)f2bf(a.z); r[3] = (short)f2bf(a.w);
    r[4] = (short)f2bf(b.x); r[5] = (short)f2bf(b.y);
    r[6] = (short)f2bf(b.z); r[7] = (short)f2bf(b.w);
    return r;
}

// ---------------------------------------------------------------------------
// f32 -> bf16 conversion of W_in, W_out only (x is stage-converted in gemm1)
// ---------------------------------------------------------------------------
#define CW1 (1024 * DMc / 8)       // W_in
#define CW2 (DMc * DIc / 8)        // W_out
__global__ __launch_bounds__(256) void convert2_kernel(const float* __restrict__ Win,
                                                       const float* __restrict__ Wout,
                                                       unsigned short* __restrict__ Wb,
                                                       unsigned short* __restrict__ Wob)
{
    int i = blockIdx.x * 256 + threadIdx.x;
    const float* src; unsigned short* dst;
    if (i < CW1)             { src = Win;  dst = Wb;  }
    else if (i < CW1 + CW2)  { src = Wout; dst = Wob; i -= CW1; }
    else return;
    float4 a = ((const float4*)src)[2 * i];
    float4 b = ((const float4*)src)[2 * i + 1];
    ushort8 o;
    o[0] = f2bf(a.x); o[1] = f2bf(a.y); o[2] = f2bf(a.z); o[3] = f2bf(a.w);
    o[4] = f2bf(b.x); o[5] = f2bf(b.y); o[6] = f2bf(b.z); o[7] = f2bf(b.w);
    ((ushort8*)dst)[i] = o;
}

// ---------------------------------------------------------------------------
// bf16 MFMA GEMM: C[M,N] = A[M,K] * B[N,K]^T, f32 accumulate.
// 128x128 tile, BK=32, 4 waves. XCD-aware bijective block swizzle (nwg%8==0).
// AF32==1: A is f32, converted to bf16 during LDS staging (x input).
// OBF==1: bf16 output. EPI==1: clip to [-1000,1000], NaN->0 (f32 path).
// ---------------------------------------------------------------------------
template<int EPI, int OBF, int AF32>
__global__ __launch_bounds__(256) void gemm_mfma(const unsigned short* __restrict__ Ab16,
                                                 const float* __restrict__ Af32,
                                                 const unsigned short* __restrict__ Bw,
                                                 float* __restrict__ Cf,
                                                 unsigned short* __restrict__ Cb,
                                                 int N, int Kd)
{
    const int nwg  = gridDim.x * gridDim.y;
    const int orig = blockIdx.y * gridDim.x + blockIdx.x;
    const int lg   = (orig & 7) * (nwg >> 3) + (orig >> 3);
    const int bx   = lg % gridDim.x;
    const int by   = lg / gridDim.x;

    __shared__ short As[128][40];
    __shared__ short Bs[128][40];
    const int tid  = threadIdx.x;
    const int lane = tid & 63;
    const int wv   = tid >> 6;
    const int wr   = wv >> 1;
    const int wc   = wv & 1;
    const int fr   = lane & 15;
    const int fq   = lane >> 4;

    const int rowA0 = by * 128;
    const int rowB0 = bx * 128;

    const int r0 = tid >> 2,        s0 = (tid & 3) << 3;
    const int r1 = (tid + 256) >> 2, s1 = s0;

    f32x4 acc[4][4];
#pragma unroll
    for (int m = 0; m < 4; ++m)
#pragma unroll
        for (int n = 0; n < 4; ++n) acc[m][n] = (f32x4){0.f, 0.f, 0.f, 0.f};

    for (int k0 = 0; k0 < Kd; k0 += 32) {
        short8 a0, a1;
        if (AF32) {
            const float* p0 = Af32 + (size_t)(rowA0 + r0) * Kd + k0 + s0;
            const float* p1 = Af32 + (size_t)(rowA0 + r1) * Kd + k0 + s1;
            a0 = pack8(*(const float4*)p0, *(const float4*)(p0 + 4));
            a1 = pack8(*(const float4*)p1, *(const float4*)(p1 + 4));
        } else {
            a0 = *(const short8*)(Ab16 + (size_t)(rowA0 + r0) * Kd + k0 + s0);
            a1 = *(const short8*)(Ab16 + (size_t)(rowA0 + r1) * Kd + k0 + s1);
        }
        short8 b0 = *(const short8*)(Bw + (size_t)(rowB0 + r0) * Kd + k0 + s0);
        short8 b1 = *(const short8*)(Bw + (size_t)(rowB0 + r1) * Kd + k0 + s1);
        __syncthreads();
        *(short8*)&As[r0][s0] = a0;
        *(short8*)&As[r1][s1] = a1;
        *(short8*)&Bs[r0][s0] = b0;
        *(short8*)&Bs[r1][s1] = b1;
        __syncthreads();

        short8 af[4], bf[4];
#pragma unroll
        for (int m = 0; m < 4; ++m)
            af[m] = *(const short8*)&As[wr * 64 + m * 16 + fr][fq << 3];
#pragma unroll
        for (int n = 0; n < 4; ++n)
            bf[n] = *(const short8*)&Bs[wc * 64 + n * 16 + fr][fq << 3];
#pragma unroll
        for (int m = 0; m < 4; ++m)
#pragma unroll
            for (int n = 0; n < 4; ++n)
                acc[m][n] = __builtin_amdgcn_mfma_f32_16x16x32_bf16(af[m], bf[n], acc[m][n], 0, 0, 0);
    }

    const int crow0 = rowA0 + wr * 64 + (fq << 2);
    const int ccol0 = rowB0 + wc * 64 + fr;
#pragma unroll
    for (int m = 0; m < 4; ++m)
#pragma unroll
        for (int n = 0; n < 4; ++n)
#pragma unroll
            for (int j = 0; j < 4; ++j) {
                float v = acc[m][n][j];
                if (EPI) v = (v != v) ? 0.f : fminf(fmaxf(v, -1000.f), 1000.f);
                size_t off = (size_t)(crow0 + m * 16 + j) * N + ccol0 + n * 16;
                if (OBF) Cb[off] = f2bf(v);
                else     Cf[off] = v;
            }
}

// ---------------------------------------------------------------------------
// Depthwise causal conv (K=4) + bias + SiLU, bf16 in (x-half of xzb), bf16 out.
// ---------------------------------------------------------------------------
__global__ __launch_bounds__(256) void conv_silu_kernel(const unsigned short* __restrict__ xzb,
                                                        const float* __restrict__ cw,
                                                        const float* __restrict__ cb,
                                                        unsigned short* __restrict__ xcb)
{
    int gid = blockIdx.x * 256 + threadIdx.x;   // over BLT*DIc/8 = 2^19
    int d8 = gid & 63;
    int l  = (gid >> 6) & (LLEN - 1);
    int b  = gid >> 17;
    int d0 = d8 << 3;

    float s[8];
#pragma unroll
    for (int j = 0; j < 8; ++j) s[j] = cb[d0 + j];
#pragma unroll
    for (int k = 0; k < KCc; ++k) {
        int ls = l + k - (KCc - 1);
        if (ls >= 0) {
            ushort8 v = *(const ushort8*)(xzb + (((size_t)(b * LLEN + ls)) << 10) + d0);
#pragma unroll
            for (int j = 0; j < 8; ++j)
                s[j] += bf2f(v[j]) * cw[(d0 + j) * KCc + k];
        }
    }
    ushort8 o;
#pragma unroll
    for (int j = 0; j < 8; ++j) {
        float v = s[j] * sigmoidf_(s[j]);
        o[j] = f2bf(v);
    }
    *(ushort8*)(xcb + ((size_t)gid << 3)) = o;
}

// ---------------------------------------------------------------------------
// x_dbl projection GEMM: [M,64] = xc_bf16[M,512] @ Wxp[64,512]^T.
// 64x64 tile, BK=16. Output SPLIT: cols 0:32 -> dtr[M,32] (dt-rank),
// cols 32:64 -> bcb[M,32] (B,C) — both packed dense for downstream reads.
// ---------------------------------------------------------------------------
__global__ __launch_bounds__(256) void gemm_xdbl(const unsigned short* __restrict__ A,
                                                 const float* __restrict__ Bw,
                                                 float* __restrict__ dtr,
                                                 float* __restrict__ bcb)
{
    __shared__ float As[16][68];
    __shared__ float Bs[16][68];
    const int tid  = threadIdx.x;
    const int tx   = tid & 15;
    const int ty   = tid >> 4;
    const int arow = tid >> 2;
    const int akq  = (tid & 3) << 2;

    const unsigned short* Ab = A + (size_t)(blockIdx.y * 64 + arow) * DIc + akq;
    const float*          Bb = Bw + (size_t)arow * DIc + akq;

    float acc[4][4] = {};

    for (int k0 = 0; k0 < DIc; k0 += 16) {
        bf16x4_t av = *(const bf16x4_t*)(Ab + k0);
        float4   bv = *(const float4*)(Bb + k0);
        __syncthreads();
        As[akq + 0][arow] = bf2f(av[0]); As[akq + 1][arow] = bf2f(av[1]);
        As[akq + 2][arow] = bf2f(av[2]); As[akq + 3][arow] = bf2f(av[3]);
        Bs[akq + 0][arow] = bv.x; Bs[akq + 1][arow] = bv.y;
        Bs[akq + 2][arow] = bv.z; Bs[akq + 3][arow] = bv.w;
        __syncthreads();
#pragma unroll
        for (int k = 0; k < 16; ++k) {
            float4 a = *(const float4*)&As[k][ty << 2];
            float4 b = *(const float4*)&Bs[k][tx << 2];
            float ar[4] = {a.x, a.y, a.z, a.w};
            float br[4] = {b.x, b.y, b.z, b.w};
#pragma unroll
            for (int i = 0; i < 4; ++i)
#pragma unroll
                for (int j = 0; j < 4; ++j)
                    acc[i][j] += ar[i] * br[j];
        }
    }

#pragma unroll
    for (int i = 0; i < 4; ++i) {
        int row = blockIdx.y * 64 + (ty << 2) + i;
        float4 v = make_float4(acc[i][0], acc[i][1], acc[i][2], acc[i][3]);
        if (tx < 8) *(float4*)(dtr + (size_t)row * 32 + (tx << 2)) = v;
        else        *(float4*)(bcb + (size_t)row * 32 + ((tx - 8) << 2)) = v;
    }
}

// ---------------------------------------------------------------------------
// f32 tiled GEMM for dt: C[M,512] = dtr[M,32] @ Wdt[512,32]^T,
// epilogue softplus(v + b_dt[col]). 64x64 tile, BK=16.
// ---------------------------------------------------------------------------
__global__ __launch_bounds__(256) void gemm_dt(const float* __restrict__ A,
                                               const float* __restrict__ Bw,
                                               const float* __restrict__ bias,
                                               float* __restrict__ C)
{
    __shared__ float As[16][68];
    __shared__ float Bs[16][68];
    const int tid  = threadIdx.x;
    const int tx   = tid & 15;
    const int ty   = tid >> 4;
    const int arow = tid >> 2;
    const int akq  = (tid & 3) << 2;

    const float* Ab = A  + (size_t)(blockIdx.y * 64 + arow) * DTRc + akq;
    const float* Bb = Bw + (size_t)(blockIdx.x * 64 + arow) * DTRc + akq;

    float acc[4][4] = {};

    for (int k0 = 0; k0 < DTRc; k0 += 16) {
        float4 av = *(const float4*)(Ab + k0);
        float4 bv = *(const float4*)(Bb + k0);
        __syncthreads();
        As[akq + 0][arow] = av.x; As[akq + 1][arow] = av.y;
        As[akq + 2][arow] = av.z; As[akq + 3][arow] = av.w;
        Bs[akq + 0][arow] = bv.x; Bs[akq + 1][arow] = bv.y;
        Bs[akq + 2][arow] = bv.z; Bs[akq + 3][arow] = bv.w;
        __syncthreads();
#pragma unroll
        for (int k = 0; k < 16; ++k) {
            float4 a = *(const float4*)&As[k][ty << 2];
            float4 b = *(const float4*)&Bs[k][tx << 2];
            float ar[4] = {a.x, a.y, a.z, a.w};
            float br[4] = {b.x, b.y, b.z, b.w};
#pragma unroll
            for (int i = 0; i < 4; ++i)
#pragma unroll
                for (int j = 0; j < 4; ++j)
                    acc[i][j] += ar[i] * br[j];
        }
    }

    float4 bd = *(const float4*)(bias + blockIdx.x * 64 + (tx << 2));
    float bb[4] = {bd.x, bd.y, bd.z, bd.w};
#pragma unroll
    for (int i = 0; i < 4; ++i) {
        float v[4];
#pragma unroll
        for (int j = 0; j < 4; ++j) {
            float s = acc[i][j] + bb[j];
            v[j] = fmaxf(s, 0.f) + log1pf(__expf(-fabsf(s)));
        }
        *(float4*)(C + (size_t)(blockIdx.y * 64 + (ty << 2) + i) * DIc
                     + blockIdx.x * 64 + (tx << 2)) = make_float4(v[0], v[1], v[2], v[3]);
    }
}

// ---------------------------------------------------------------------------
// Chunked parallel scan. dt f32 in dtz; B/C f32 packed in bcb[8192][32];
// z bf16 in xzb cols 512+; xc bf16 in xcb. hstate bf16 (h_end / h_in).
// ---------------------------------------------------------------------------
__device__ __forceinline__ size_t hs_off(int b, int c, int s, int d) {
    return ((size_t)((b * NCH + c) * DSc + s) << 9) + d;
}

__global__ __launch_bounds__(256) void scan_phase1(const float* __restrict__ dtz,
                                                   const unsigned short* __restrict__ xcb,
                                                   const float* __restrict__ bcb,
                                                   const float* __restrict__ A_log,
                                                   unsigned short* __restrict__ hstate,
                                                   float* __restrict__ sdtbuf)
{
    int half = blockIdx.x & 1;
    int c    = (blockIdx.x >> 1) & (NCH - 1);
    int b    = blockIdx.x >> 8;
    int d    = (half << 8) + threadIdx.x;
    int row0 = b * LLEN + c * CLEN;

    __shared__ float bc[CLEN][32];   // [t][0:16]=B, [t][16:32]=C
    {
        int r = threadIdx.x >> 5, col = threadIdx.x & 31;
        const float* src = bcb + (size_t)row0 * 32;
        bc[r][col]     = src[r * 32 + col];
        bc[r + 8][col] = src[(r + 8) * 32 + col];
    }

    float A[DSc];
#pragma unroll
    for (int s = 0; s < DSc; ++s) A[s] = -__expf(A_log[d * DSc + s]);

    float dtv[CLEN], xcv[CLEN];
#pragma unroll
    for (int t = 0; t < CLEN; ++t) {
        dtv[t] = dtz[((size_t)(row0 + t) << 9) + d];
        xcv[t] = bf2f(xcb[((size_t)(row0 + t) << 9) + d]);
    }
    __syncthreads();

    float h[DSc] = {};
    float Sdt = 0.f;
#pragma unroll
    for (int t = 0; t < CLEN; ++t) {
        float dBx = dtv[t] * xcv[t];
        Sdt += dtv[t];
#pragma unroll
        for (int s = 0; s < DSc; ++s)
            h[s] = __expf(dtv[t] * A[s]) * h[s] + dBx * bc[t][s];
    }
#pragma unroll
    for (int s = 0; s < DSc; ++s) hstate[hs_off(b, c, s, d)] = f2bf(h[s]);
    sdtbuf[((size_t)(b * NCH + c) << 9) + d] = Sdt;
}

__global__ __launch_bounds__(64) void scan_phase2(unsigned short* __restrict__ hstate,
                                                  const float* __restrict__ sdtbuf,
                                                  const float* __restrict__ A_log)
{
    int gid = blockIdx.x * 64 + threadIdx.x;    // over B*DSc*DIc = 32768
    int d = gid & (DIc - 1);
    int s = (gid >> 9) & (DSc - 1);
    int b = gid >> 13;

    float A = -__expf(A_log[d * DSc + s]);
    float h = 0.f;
    for (int c = 0; c < NCH; ++c) {
        size_t o = hs_off(b, c, s, d);
        float he  = bf2f(hstate[o]);
        float Sdt = sdtbuf[((size_t)(b * NCH + c) << 9) + d];
        hstate[o] = f2bf(h);
        h = __expf(A * Sdt) * h + he;
    }
}

__global__ __launch_bounds__(256) void scan_phase3(const float* __restrict__ dtz,
                                                   const unsigned short* __restrict__ xcb,
                                                   const float* __restrict__ bcb,
                                                   const unsigned short* __restrict__ xzb,
                                                   const unsigned short* __restrict__ hstate,
                                                   const float* __restrict__ A_log,
                                                   const float* __restrict__ Dp,
                                                   unsigned short* __restrict__ yb)
{
    int half = blockIdx.x & 1;
    int c    = (blockIdx.x >> 1) & (NCH - 1);
    int b    = blockIdx.x >> 8;
    int d    = (half << 8) + threadIdx.x;
    int row0 = b * LLEN + c * CLEN;

    __shared__ float bc[CLEN][32];   // [t][0:16]=B, [t][16:32]=C
    {
        int r = threadIdx.x >> 5, col = threadIdx.x & 31;
        const float* src = bcb + (size_t)row0 * 32;
        bc[r][col]     = src[r * 32 + col];
        bc[r + 8][col] = src[(r + 8) * 32 + col];
    }

    float A[DSc];
#pragma unroll
    for (int s = 0; s < DSc; ++s) A[s] = -__expf(A_log[d * DSc + s]);
    float Dv = Dp[d];

    float dtv[CLEN], xcv[CLEN], zv[CLEN];
#pragma unroll
    for (int t = 0; t < CLEN; ++t) {
        dtv[t] = dtz[((size_t)(row0 + t) << 9) + d];
        xcv[t] = bf2f(xcb[((size_t)(row0 + t) << 9) + d]);
        zv[t]  = bf2f(xzb[((size_t)(row0 + t) << 10) + DIc + d]);
    }

    float h[DSc];
#pragma unroll
    for (int s = 0; s < DSc; ++s) h[s] = bf2f(hstate[hs_off(b, c, s, d)]);  // h_in
    __syncthreads();

#pragma unroll
    for (int t = 0; t < CLEN; ++t) {
        float dBx = dtv[t] * xcv[t];
        float acc = 0.f;
#pragma unroll
        for (int s = 0; s < DSc; ++s) {
            float dA = __expf(dtv[t] * A[s]);
            h[s] = dA * h[s] + dBx * bc[t][s];
            acc += h[s] * bc[t][DSc + s];
        }
        float yv = (acc + xcv[t] * Dv) * (zv[t] * sigmoidf_(zv[t]));
        yb[((size_t)(row0 + t) << 9) + d] = f2bf(yv);
    }
}

// ---------------------------------------------------------------------------
extern "C" void kernel_launch(void* const* d_in, const int* in_sizes, int n_in,
                              void* d_out, int out_size, void* d_ws, size_t ws_size,
                              hipStream_t stream)
{
    const float* x      = (const float*)d_in[0];
    const float* W_in   = (const float*)d_in[1];
    const float* conv_w = (const float*)d_in[2];
    const float* conv_b = (const float*)d_in[3];
    const float* W_xp   = (const float*)d_in[4];
    const float* W_dt   = (const float*)d_in[5];
    const float* b_dt   = (const float*)d_in[6];
    const float* A_log  = (const float*)d_in[7];
    const float* D_par  = (const float*)d_in[8];
    const float* W_out  = (const float*)d_in[9];
    float* out = (float*)d_out;

    // workspace layout (~64 MB)
    unsigned short* yb   = (unsigned short*)d_ws;            // [8192,512]  bf16: y
    unsigned short* xzb  = yb  + (size_t)BLT * DIc;          // [8192,1024] bf16: xz
    unsigned short* xcb  = xzb + (size_t)BLT * 1024;         // [8192,512]  bf16: xc
    unsigned short* Wb   = xcb + (size_t)BLT * DIc;          // [1024,512]  bf16
    unsigned short* Wob  = Wb  + (size_t)1024 * DMc;         // [512,512]   bf16
    float* dtr    = (float*)(Wob + (size_t)DMc * DIc);       // [8192,32]   f32: dt-rank
    float* bcb    = dtr + (size_t)BLT * 32;                  // [8192,32]   f32: B,C
    float* dtz    = bcb + (size_t)BLT * 32;                  // [8192,512]  f32: dt
    unsigned short* hstate = (unsigned short*)(dtz + (size_t)BLT * DIc); // [4,128,16,512] bf16
    float* sdtbuf = (float*)(hstate + (size_t)BBc * NCH * DSc * DIc);    // [4,128,512] f32

    // 0. f32 -> bf16 conversions (W_in, W_out)
    convert2_kernel<<<(CW1 + CW2 + 255) / 256, 256, 0, stream>>>(W_in, W_out, Wb, Wob);

    // 1. xz = x @ W_in^T (M=8192,N=1024,K=512), f32 A staged->bf16, bf16 out
    gemm_mfma<0, 1, 1><<<dim3(1024 / 128, BLT / 128), 256, 0, stream>>>(
        nullptr, x, Wb, nullptr, xzb, 1024, DMc);

    // 2. depthwise causal conv + SiLU -> xcb (bf16, 8-wide)
    conv_silu_kernel<<<(BLT * DIc / 8) / 256, 256, 0, stream>>>(xzb, conv_w, conv_b, xcb);

    // 3. x_dbl = xc @ W_xproj^T, split-packed -> dtr[:,32], bcb[:,32]
    gemm_xdbl<<<dim3(1, BLT / 64), 256, 0, stream>>>(xcb, W_xp, dtr, bcb);

    // 4. dt = softplus(dtr @ W_dt^T + b_dt) -> dtz (f32)
    gemm_dt<<<dim3(DIc / 64, BLT / 64), 256, 0, stream>>>(dtr, W_dt, b_dt, dtz);

    // 5. chunked parallel scan; y (bf16) into yb
    scan_phase1<<<BBc * NCH * 2, 256, 0, stream>>>(dtz, xcb, bcb, A_log, hstate, sdtbuf);
    scan_phase2<<<(BBc * DSc * DIc) / 64, 64, 0, stream>>>(hstate, sdtbuf, A_log);
    scan_phase3<<<BBc * NCH * 2, 256, 0, stream>>>(dtz, xcb, bcb, xzb, hstate,
                                                   A_log, D_par, yb);

    // 6. out = clip(y @ W_out^T) (M=8192,N=512,K=512), f32 out
    gemm_mfma<1, 0, 0><<<dim3(DMc / 128, BLT / 128), 256, 0, stream>>>(
        yb, nullptr, Wob, out, nullptr, DMc, DMc);
}

// Round 12
// 179.300 us; speedup vs baseline: 1.2649x; 1.0521x over previous
//
#include <hip/hip_runtime.h>
#include <math.h>

// Problem constants (from reference): DM=512, DS=16, K=4, EXPAND=1
#define DMc   512
#define DIc   512
#define DSc   16
#define KCc   4
#define DTRc  32          // (512+15)//16
#define NXDc  64          // DTR + 2*DS
#define LLEN  2048
#define BBc   4
#define BLT   (BBc*LLEN)  // 8192

// chunked scan config
#define NCH   128         // chunks per sequence
#define CLEN  (LLEN/NCH)  // 16

typedef __attribute__((ext_vector_type(8))) short short8;
typedef __attribute__((ext_vector_type(8))) unsigned short ushort8;
typedef __attribute__((ext_vector_type(4))) float f32x4;

__device__ __forceinline__ float sigmoidf_(float x) { return 1.f / (1.f + __expf(-x)); }

// round-to-nearest-even f32 -> bf16 bits
__device__ __forceinline__ unsigned short f2bf(float x) {
    unsigned int u = __float_as_uint(x);
    u = (u + 0x7FFFu + ((u >> 16) & 1u)) >> 16;
    return (unsigned short)u;
}

// ---------------------------------------------------------------------------
// fused f32 -> bf16 conversion of x, W_in, W_out (one launch, 8 elems/thread)
// ---------------------------------------------------------------------------
#define CN1 (BLT * DMc / 8)        // x
#define CN2 (1024 * DMc / 8)       // W_in
#define CN3 (DMc * DIc / 8)        // W_out
__global__ __launch_bounds__(256) void convert3_kernel(const float* __restrict__ x,
                                                       const float* __restrict__ Win,
                                                       const float* __restrict__ Wout,
                                                       unsigned short* __restrict__ xb,
                                                       unsigned short* __restrict__ Wb,
                                                       unsigned short* __restrict__ Wob)
{
    int i = blockIdx.x * 256 + threadIdx.x;
    const float* src; unsigned short* dst;
    if (i < CN1)                  { src = x;    dst = xb;  }
    else if (i < CN1 + CN2)       { src = Win;  dst = Wb;  i -= CN1; }
    else if (i < CN1 + CN2 + CN3) { src = Wout; dst = Wob; i -= CN1 + CN2; }
    else return;
    float4 a = ((const float4*)src)[2 * i];
    float4 b = ((const float4*)src)[2 * i + 1];
    ushort8 o;
    o[0] = f2bf(a.x); o[1] = f2bf(a.y); o[2] = f2bf(a.z); o[3] = f2bf(a.w);
    o[4] = f2bf(b.x); o[5] = f2bf(b.y); o[6] = f2bf(b.z); o[7] = f2bf(b.w);
    ((ushort8*)dst)[i] = o;
}

// ---------------------------------------------------------------------------
// f32 tiled GEMM: C[M,N] = A[M,K] * B[N,K]^T, strides lda/ldb/ldc.
// 64x64 tile, BK=16, 256 threads, 4x4 micro-tile per thread.
// EPI==0: plain. EPI==2: v = softplus(v + bias[col]) (dt projection).
// ---------------------------------------------------------------------------
template<int EPI>
__global__ __launch_bounds__(256) void gemm_bt_f32(const float* __restrict__ A,
                                                   const float* __restrict__ Bw,
                                                   const float* __restrict__ bias,
                                                   float* __restrict__ C,
                                                   int M, int N, int Kd,
                                                   int lda, int ldb, int ldc)
{
    __shared__ float As[16][68];
    __shared__ float Bs[16][68];
    const int tid  = threadIdx.x;
    const int tx   = tid & 15;
    const int ty   = tid >> 4;
    const int arow = tid >> 2;
    const int akq  = (tid & 3) << 2;

    const float* Ab = A  + (size_t)(blockIdx.y * 64 + arow) * lda + akq;
    const float* Bb = Bw + (size_t)(blockIdx.x * 64 + arow) * ldb + akq;

    float acc[4][4] = {};

    for (int k0 = 0; k0 < Kd; k0 += 16) {
        float4 av = *(const float4*)(Ab + k0);
        float4 bv = *(const float4*)(Bb + k0);
        __syncthreads();
        As[akq + 0][arow] = av.x; As[akq + 1][arow] = av.y;
        As[akq + 2][arow] = av.z; As[akq + 3][arow] = av.w;
        Bs[akq + 0][arow] = bv.x; Bs[akq + 1][arow] = bv.y;
        Bs[akq + 2][arow] = bv.z; Bs[akq + 3][arow] = bv.w;
        __syncthreads();
#pragma unroll
        for (int k = 0; k < 16; ++k) {
            float4 a = *(const float4*)&As[k][ty << 2];
            float4 b = *(const float4*)&Bs[k][tx << 2];
            float ar[4] = {a.x, a.y, a.z, a.w};
            float br[4] = {b.x, b.y, b.z, b.w};
#pragma unroll
            for (int i = 0; i < 4; ++i)
#pragma unroll
                for (int j = 0; j < 4; ++j)
                    acc[i][j] += ar[i] * br[j];
        }
    }

    float4 bv = make_float4(0.f, 0.f, 0.f, 0.f);
    if (EPI == 2) bv = *(const float4*)(bias + blockIdx.x * 64 + (tx << 2));
#pragma unroll
    for (int i = 0; i < 4; ++i) {
        float v[4] = {acc[i][0], acc[i][1], acc[i][2], acc[i][3]};
        if (EPI == 2) {
            float bb[4] = {bv.x, bv.y, bv.z, bv.w};
#pragma unroll
            for (int j = 0; j < 4; ++j) {
                float s = v[j] + bb[j];
                v[j] = fmaxf(s, 0.f) + log1pf(__expf(-fabsf(s)));
            }
        }
        *(float4*)(C + (size_t)(blockIdx.y * 64 + (ty << 2) + i) * ldc
                     + blockIdx.x * 64 + (tx << 2)) = make_float4(v[0], v[1], v[2], v[3]);
    }
}

// ---------------------------------------------------------------------------
// bf16 MFMA GEMM: C[M,N] = A[M,K] * B[N,K]^T, f32 accumulate/output.
// 128x128 tile, BK=32, 4 waves. XCD-aware bijective block swizzle (nwg%8==0).
// EPI==1: clip to [-1000,1000], NaN->0.
// ---------------------------------------------------------------------------
template<int EPI>
__global__ __launch_bounds__(256) void gemm_mfma(const unsigned short* __restrict__ A,
                                                 const unsigned short* __restrict__ Bw,
                                                 float* __restrict__ C,
                                                 int M, int N, int Kd)
{
    // XCD swizzle: blocks sharing an A-panel co-reside on one XCD's L2
    const int nwg  = gridDim.x * gridDim.y;
    const int orig = blockIdx.y * gridDim.x + blockIdx.x;
    const int lg   = (orig & 7) * (nwg >> 3) + (orig >> 3);
    const int bx   = lg % gridDim.x;
    const int by   = lg / gridDim.x;

    __shared__ short As[128][40];
    __shared__ short Bs[128][40];
    const int tid  = threadIdx.x;
    const int lane = tid & 63;
    const int wv   = tid >> 6;
    const int wr   = wv >> 1;
    const int wc   = wv & 1;
    const int fr   = lane & 15;
    const int fq   = lane >> 4;

    const int rowA0 = by * 128;
    const int rowB0 = bx * 128;

    const int r0 = tid >> 2,        s0 = (tid & 3) << 3;
    const int r1 = (tid + 256) >> 2, s1 = s0;

    f32x4 acc[4][4];
#pragma unroll
    for (int m = 0; m < 4; ++m)
#pragma unroll
        for (int n = 0; n < 4; ++n) acc[m][n] = (f32x4){0.f, 0.f, 0.f, 0.f};

    for (int k0 = 0; k0 < Kd; k0 += 32) {
        short8 a0 = *(const short8*)(A  + (size_t)(rowA0 + r0) * Kd + k0 + s0);
        short8 a1 = *(const short8*)(A  + (size_t)(rowA0 + r1) * Kd + k0 + s1);
        short8 b0 = *(const short8*)(Bw + (size_t)(rowB0 + r0) * Kd + k0 + s0);
        short8 b1 = *(const short8*)(Bw + (size_t)(rowB0 + r1) * Kd + k0 + s1);
        __syncthreads();
        *(short8*)&As[r0][s0] = a0;
        *(short8*)&As[r1][s1] = a1;
        *(short8*)&Bs[r0][s0] = b0;
        *(short8*)&Bs[r1][s1] = b1;
        __syncthreads();

        short8 af[4], bf[4];
#pragma unroll
        for (int m = 0; m < 4; ++m)
            af[m] = *(const short8*)&As[wr * 64 + m * 16 + fr][fq << 3];
#pragma unroll
        for (int n = 0; n < 4; ++n)
            bf[n] = *(const short8*)&Bs[wc * 64 + n * 16 + fr][fq << 3];
#pragma unroll
        for (int m = 0; m < 4; ++m)
#pragma unroll
            for (int n = 0; n < 4; ++n)
                acc[m][n] = __builtin_amdgcn_mfma_f32_16x16x32_bf16(af[m], bf[n], acc[m][n], 0, 0, 0);
    }

    const int crow0 = rowA0 + wr * 64 + (fq << 2);
    const int ccol0 = rowB0 + wc * 64 + fr;
#pragma unroll
    for (int m = 0; m < 4; ++m)
#pragma unroll
        for (int n = 0; n < 4; ++n)
#pragma unroll
            for (int j = 0; j < 4; ++j) {
                float v = acc[m][n][j];
                if (EPI) v = (v != v) ? 0.f : fminf(fmaxf(v, -1000.f), 1000.f);
                C[(size_t)(crow0 + m * 16 + j) * N + ccol0 + n * 16] = v;
            }
}

// ---------------------------------------------------------------------------
// Depthwise causal conv (K=4) + bias + SiLU, f32 in/out, 4 channels/thread.
// ---------------------------------------------------------------------------
__global__ __launch_bounds__(256) void conv_silu_kernel(const float* __restrict__ xz,
                                                        const float* __restrict__ cw,
                                                        const float* __restrict__ cb,
                                                        float* __restrict__ xc)
{
    int gid = blockIdx.x * 256 + threadIdx.x;   // over BLT*DIc/4 = 2^20
    int d4 = gid & 127;
    int l  = (gid >> 7) & (LLEN - 1);
    int b  = gid >> 18;
    int d0 = d4 << 2;

    float4 s = *(const float4*)(cb + d0);
    float sv[4] = {s.x, s.y, s.z, s.w};
#pragma unroll
    for (int k = 0; k < KCc; ++k) {
        int ls = l + k - (KCc - 1);
        if (ls >= 0) {
            float4 v = *(const float4*)(xz + (((size_t)(b * LLEN + ls)) << 10) + d0);
            float vv[4] = {v.x, v.y, v.z, v.w};
#pragma unroll
            for (int j = 0; j < 4; ++j)
                sv[j] += vv[j] * cw[(d0 + j) * KCc + k];
        }
    }
    float4 o;
    o.x = sv[0] * sigmoidf_(sv[0]);
    o.y = sv[1] * sigmoidf_(sv[1]);
    o.z = sv[2] * sigmoidf_(sv[2]);
    o.w = sv[3] * sigmoidf_(sv[3]);
    *(float4*)(xc + ((size_t)gid << 2)) = o;
}

// ---------------------------------------------------------------------------
// Chunked parallel scan. dt precomputed by GEMM into the dead x-half of xz
// (dtz[row*1024 + d]); z lives at dtz[row*1024 + 512 + d].
// hstate[b,c,s,d]: h_end after phase1, h_in after phase2 (f32).
// Register-preload each thread's chunk of dt/xc/z; B/C slice staged in LDS.
// ---------------------------------------------------------------------------
__device__ __forceinline__ size_t hs_off(int b, int c, int s, int d) {
    return ((size_t)((b * NCH + c) * DSc + s) << 9) + d;
}

__global__ __launch_bounds__(256) void scan_phase1(const float* __restrict__ dtz,
                                                   const float* __restrict__ xc,
                                                   const float* __restrict__ xdbl,
                                                   const float* __restrict__ A_log,
                                                   float* __restrict__ hstate,
                                                   float* __restrict__ sdtbuf)
{
    int half = blockIdx.x & 1;
    int c    = (blockIdx.x >> 1) & (NCH - 1);
    int b    = blockIdx.x >> 8;
    int d    = (half << 8) + threadIdx.x;
    int row0 = b * LLEN + c * CLEN;

    __shared__ float bc[CLEN][32];   // [t][0:16]=B
    {
        int r = threadIdx.x >> 4, col = (threadIdx.x & 15) << 1;
        const float* src = xdbl + (size_t)(row0 + r) * NXDc + DTRc + col;
        bc[r][col] = src[0]; bc[r][col + 1] = src[1];
    }

    float A[DSc];
#pragma unroll
    for (int s = 0; s < DSc; ++s) A[s] = -__expf(A_log[d * DSc + s]);

    float dtv[CLEN], xcv[CLEN];
#pragma unroll
    for (int t = 0; t < CLEN; ++t) {
        dtv[t] = dtz[((size_t)(row0 + t) << 10) + d];
        xcv[t] = xc [((size_t)(row0 + t) << 9) + d];
    }
    __syncthreads();

    float h[DSc] = {};
    float Sdt = 0.f;
#pragma unroll
    for (int t = 0; t < CLEN; ++t) {
        float dBx = dtv[t] * xcv[t];
        Sdt += dtv[t];
#pragma unroll
        for (int s = 0; s < DSc; ++s)
            h[s] = __expf(dtv[t] * A[s]) * h[s] + dBx * bc[t][s];
    }
#pragma unroll
    for (int s = 0; s < DSc; ++s) hstate[hs_off(b, c, s, d)] = h[s];
    sdtbuf[((size_t)(b * NCH + c) << 9) + d] = Sdt;
}

__global__ __launch_bounds__(64) void scan_phase2(float* __restrict__ hstate,
                                                  const float* __restrict__ sdtbuf,
                                                  const float* __restrict__ A_log)
{
    int gid = blockIdx.x * 64 + threadIdx.x;    // over B*DSc*DIc = 32768
    int d = gid & (DIc - 1);
    int s = (gid >> 9) & (DSc - 1);
    int b = gid >> 13;

    float A = -__expf(A_log[d * DSc + s]);
    float h = 0.f;
    for (int c = 0; c < NCH; ++c) {
        size_t o = hs_off(b, c, s, d);
        float he  = hstate[o];
        float Sdt = sdtbuf[((size_t)(b * NCH + c) << 9) + d];
        hstate[o] = h;
        h = __expf(A * Sdt) * h + he;
    }
}

__global__ __launch_bounds__(256) void scan_phase3(const float* __restrict__ dtz,
                                                   const float* __restrict__ xc,
                                                   const float* __restrict__ xdbl,
                                                   const float* __restrict__ hstate,
                                                   const float* __restrict__ A_log,
                                                   const float* __restrict__ Dp,
                                                   unsigned short* __restrict__ yb)
{
    int half = blockIdx.x & 1;
    int c    = (blockIdx.x >> 1) & (NCH - 1);
    int b    = blockIdx.x >> 8;
    int d    = (half << 8) + threadIdx.x;
    int row0 = b * LLEN + c * CLEN;

    __shared__ float bc[CLEN][32];   // [t][0:16]=B, [t][16:32]=C
    {
        int r = threadIdx.x >> 4, col = (threadIdx.x & 15) << 1;
        const float* src = xdbl + (size_t)(row0 + r) * NXDc + DTRc + col;
        bc[r][col] = src[0]; bc[r][col + 1] = src[1];
    }

    float A[DSc];
#pragma unroll
    for (int s = 0; s < DSc; ++s) A[s] = -__expf(A_log[d * DSc + s]);
    float Dv = Dp[d];

    float dtv[CLEN], xcv[CLEN], zv[CLEN];
#pragma unroll
    for (int t = 0; t < CLEN; ++t) {
        dtv[t] = dtz[((size_t)(row0 + t) << 10) + d];
        xcv[t] = xc [((size_t)(row0 + t) << 9) + d];
        zv[t]  = dtz[((size_t)(row0 + t) << 10) + DIc + d];
    }

    float h[DSc];
#pragma unroll
    for (int s = 0; s < DSc; ++s) h[s] = hstate[hs_off(b, c, s, d)];  // h_in
    __syncthreads();

#pragma unroll
    for (int t = 0; t < CLEN; ++t) {
        float dBx = dtv[t] * xcv[t];
        float acc = 0.f;
#pragma unroll
        for (int s = 0; s < DSc; ++s) {
            float dA = __expf(dtv[t] * A[s]);
            h[s] = dA * h[s] + dBx * bc[t][s];
            acc += h[s] * bc[t][DSc + s];
        }
        float yv = (acc + xcv[t] * Dv) * (zv[t] * sigmoidf_(zv[t]));
        yb[((size_t)(row0 + t) << 9) + d] = f2bf(yv);
    }
}

// ---------------------------------------------------------------------------
extern "C" void kernel_launch(void* const* d_in, const int* in_sizes, int n_in,
                              void* d_out, int out_size, void* d_ws, size_t ws_size,
                              hipStream_t stream)
{
    const float* x      = (const float*)d_in[0];
    const float* W_in   = (const float*)d_in[1];
    const float* conv_w = (const float*)d_in[2];
    const float* conv_b = (const float*)d_in[3];
    const float* W_xp   = (const float*)d_in[4];
    const float* W_dt   = (const float*)d_in[5];
    const float* b_dt   = (const float*)d_in[6];
    const float* A_log  = (const float*)d_in[7];
    const float* D_par  = (const float*)d_in[8];
    const float* W_out  = (const float*)d_in[9];
    float* out = (float*)d_out;

    float* ws   = (float*)d_ws;
    float* xz   = ws;                                   // [8192,1024] f32; cols 0..511 reused for dt after conv
    float* xc   = xz + (size_t)BLT * 1024;              // [8192,512]  f32
    float* xdbl = xc + (size_t)BLT * DIc;               // [8192,64]   f32
    unsigned short* xb  = (unsigned short*)(xdbl + (size_t)BLT * NXDc); // [8192,512] bf16 (x, then y)
    unsigned short* Wb  = xb + (size_t)BLT * DIc;       // [1024,512] bf16
    unsigned short* Wob = Wb + (size_t)1024 * DMc;      // [512,512]  bf16
    float* hstate = (float*)(Wob + (size_t)DMc * DIc);  // [4,128,16,512] f32
    float* sdtbuf = hstate + (size_t)BBc * NCH * DSc * DIc; // [4,128,512] f32

    // 0. f32 -> bf16 conversions (x, W_in, W_out) in one launch
    convert3_kernel<<<(CN1 + CN2 + CN3 + 255) / 256, 256, 0, stream>>>(
        x, W_in, W_out, xb, Wb, Wob);

    // 1. xz = x @ W_in^T      (M=8192, N=1024, K=512) via bf16 MFMA (swizzled)
    gemm_mfma<0><<<dim3(1024 / 128, BLT / 128), 256, 0, stream>>>(xb, Wb, xz, BLT, 1024, DMc);

    // 2. depthwise causal conv + SiLU -> xc (float4 x4 channels)
    conv_silu_kernel<<<(BLT * DIc / 4) / 256, 256, 0, stream>>>(xz, conv_w, conv_b, xc);

    // 3. x_dbl = xc @ W_xproj^T   (M=8192, N=64, K=512)
    gemm_bt_f32<0><<<dim3(1, BLT / 64), 256, 0, stream>>>(xc, W_xp, nullptr, xdbl,
                                                          BLT, NXDc, DIc, DIc, DIc, NXDc);

    // 4. dt = softplus(x_dbl[:, :32] @ W_dt^T + b_dt) -> dead x-half of xz (ldc=1024)
    gemm_bt_f32<2><<<dim3(DIc / 64, BLT / 64), 256, 0, stream>>>(xdbl, W_dt, b_dt, xz,
                                                                 BLT, DIc, DTRc, NXDc, DTRc, 1024);

    // 5. chunked parallel scan; y (bf16) into xb
    scan_phase1<<<BBc * NCH * 2, 256, 0, stream>>>(xz, xc, xdbl, A_log, hstate, sdtbuf);
    scan_phase2<<<(BBc * DSc * DIc) / 64, 64, 0, stream>>>(hstate, sdtbuf, A_log);
    scan_phase3<<<BBc * NCH * 2, 256, 0, stream>>>(xz, xc, xdbl, hstate, A_log, D_par, xb);

    // 6. out = clip(y @ W_out^T)  (M=8192, N=512, K=512) via bf16 MFMA (swizzled)
    gemm_mfma<1><<<dim3(DMc / 128, BLT / 128), 256, 0, stream>>>(xb, Wob, out, BLT, DMc, DMc);
}